// Round 1
// baseline (1308.933 us; speedup 1.0000x reference)
//
#include <hip/hip_runtime.h>

#define T_TOK 8192
#define DIM   1024
#define FFD   4096
#define NEXP  16

typedef __bf16 bf16_t;
typedef bf16_t bf16x4 __attribute__((ext_vector_type(4)));
typedef bf16_t bf16x8 __attribute__((ext_vector_type(8)));
typedef float  f32x4  __attribute__((ext_vector_type(4)));

__device__ __forceinline__ void gload_lds16(const void* g, void* l) {
  __builtin_amdgcn_global_load_lds((__attribute__((address_space(1))) void*)(g),
                                   (__attribute__((address_space(3))) void*)(l),
                                   16, 0, 0);
}

// ---------------- RMSNorm + gate + top-2 routing (one block per token) -------
// Also records each token's two (expert, slot) pairs so the final combine
// kernel can gather its two partial rows without atomics.
__global__ __launch_bounds__(256) void k_norm_gate(
    const float* __restrict__ x, const float* __restrict__ lnw,
    const float* __restrict__ gw, const float* __restrict__ gb,
    bf16_t* __restrict__ xt, int* __restrict__ cnt,
    int* __restrict__ stok, float* __restrict__ swgt,
    int* __restrict__ tslot)
{
  const int t = blockIdx.x;
  const int tid = threadIdx.x;
  const int wave = tid >> 6, lane = tid & 63;

  float4 v = ((const float4*)(x + (size_t)t * DIM))[tid];
  float ss = v.x*v.x + v.y*v.y + v.z*v.z + v.w*v.w;
  #pragma unroll
  for (int off = 32; off > 0; off >>= 1) ss += __shfl_down(ss, off, 64);

  __shared__ float red[4];
  __shared__ float racc[4][16];
  if (lane == 0) red[wave] = ss;
  __syncthreads();
  float r = rsqrtf((red[0]+red[1]+red[2]+red[3]) * (1.0f/DIM) + 1e-6f);

  float4 lw = ((const float4*)lnw)[tid];
  float nv[4];
  nv[0] = v.x*r*lw.x; nv[1] = v.y*r*lw.y; nv[2] = v.z*r*lw.z; nv[3] = v.w*r*lw.w;
  bf16x4 nb; nb[0]=(bf16_t)nv[0]; nb[1]=(bf16_t)nv[1]; nb[2]=(bf16_t)nv[2]; nb[3]=(bf16_t)nv[3];
  ((bf16x4*)(xt + (size_t)t * DIM))[tid] = nb;

  // gate logits: fp32 (expert-selection must match np reference)
  float acc[16];
  #pragma unroll
  for (int e=0;e<16;e++) acc[e]=0.f;
  #pragma unroll
  for (int j=0;j<4;j++){
    const float4* row = (const float4*)(gw + ((size_t)(tid*4+j))*16);
    #pragma unroll
    for (int q=0;q<4;q++){
      float4 g = row[q];
      acc[q*4+0] += nv[j]*g.x;
      acc[q*4+1] += nv[j]*g.y;
      acc[q*4+2] += nv[j]*g.z;
      acc[q*4+3] += nv[j]*g.w;
    }
  }
  #pragma unroll
  for (int e=0;e<16;e++){
    #pragma unroll
    for (int off=32;off>0;off>>=1) acc[e] += __shfl_down(acc[e], off, 64);
  }
  if (lane==0){
    #pragma unroll
    for (int e=0;e<16;e++) racc[wave][e]=acc[e];
  }
  __syncthreads();
  if (tid==0){
    float lg[16];
    #pragma unroll
    for (int e=0;e<16;e++) lg[e] = racc[0][e]+racc[1][e]+racc[2][e]+racc[3][e] + gb[e];
    int i0=0; float v0=lg[0];
    for (int e=1;e<16;e++) if (lg[e]>v0){v0=lg[e]; i0=e;}
    int i1=-1; float v1=-3.4e38f;
    for (int e=0;e<16;e++) if (e!=i0 && lg[e]>v1){v1=lg[e]; i1=e;}
    float ex = expf(v1-v0);
    float s0 = 1.0f/(1.0f+ex);
    float s1 = ex * s0;
    int p0 = atomicAdd(&cnt[i0],1);
    stok[i0*T_TOK+p0]=t; swgt[i0*T_TOK+p0]=s0;
    int p1 = atomicAdd(&cnt[i1],1);
    stok[i1*T_TOK+p1]=t; swgt[i1*T_TOK+p1]=s1;
    tslot[2*t+0] = (i0<<16) | p0;     // expert in hi16, slot in lo16 (p<=8192)
    tslot[2*t+1] = (i1<<16) | p1;
  }
}

// ---------------- tiny prefix sum over 16 expert counts ----------------------
__global__ void k_offsets(const int* __restrict__ cnt, int* __restrict__ offs){
  if (threadIdx.x==0){
    int s=0;
    for (int e=0;e<NEXP;e++){ offs[e]=s; s+=cnt[e]; }
    offs[NEXP]=s;
  }
}

// ---------------- fp32 [E][R][C] -> bf16 [E][C][R] (convert + transpose) -----
__global__ __launch_bounds__(256) void k_transpose(
    const float* __restrict__ in, bf16_t* __restrict__ out, int R, int C)
{
  __shared__ float tile[64][68];
  const int e = blockIdx.z;
  const int r0 = blockIdx.y*64, c0 = blockIdx.x*64;
  const int tr = threadIdx.x >> 4, tc4 = (threadIdx.x & 15)*4;
  const float* src = in + ((size_t)e*R + r0)*C + c0;
  #pragma unroll
  for (int i=0;i<4;i++){
    int rr = tr + i*16;
    float4 vv = *(const float4*)(src + (size_t)rr*C + tc4);
    tile[rr][tc4+0]=vv.x; tile[rr][tc4+1]=vv.y; tile[rr][tc4+2]=vv.z; tile[rr][tc4+3]=vv.w;
  }
  __syncthreads();
  bf16_t* dst = out + ((size_t)e*C + c0)*R + r0;
  #pragma unroll
  for (int i=0;i<4;i++){
    int cc = tr + i*16;
    bf16x4 b;
    b[0]=(bf16_t)tile[tc4+0][cc];
    b[1]=(bf16_t)tile[tc4+1][cc];
    b[2]=(bf16_t)tile[tc4+2][cc];
    b[3]=(bf16_t)tile[tc4+3][cc];
    *(bf16x4*)(dst + (size_t)cc*R + tc4) = b;
  }
}

// ---------------- routed GEMM (m97 structure), 128x128 tile, BK=64 -----------
// LDS K-blocks are XOR-swizzled: physical_block = logical_block ^ (row & 7).
// Swizzle is applied on the *global source column* at staging time (the
// global_load_lds LDS destination is HW-fixed to lane*16B) and undone at
// fragment-read time. Breaks the 16-way bank conflict of the 128B-row layout.
// G1:  h[off_e+row] = relu(gather(xt) @ wiT^T) * gate_w   (bf16 out)
// !G1: y2[off_e+row] = h_rows @ woT^T                     (fp32 plain stores;
//      per-token combine happens in k_combine — no atomics needed since K=2)
template<int KD, bool G1>
__global__ __launch_bounds__(256) void k_gemm(
    const bf16_t* __restrict__ A0, const bf16_t* __restrict__ Bt,
    const int* __restrict__ cnt, const int* __restrict__ offs,
    const int* __restrict__ stok, const float* __restrict__ swgt,
    bf16_t* __restrict__ Hout, float* __restrict__ Out)
{
  const int e  = blockIdx.z;
  const int cn = cnt[e];
  const int m0 = blockIdx.y * 128;
  if (m0 >= cn) return;
  const int n0 = blockIdx.x * 128;
  const int oe = offs[e];
  constexpr int NR = G1 ? FFD : DIM;

  __shared__ bf16_t As[128*64];
  __shared__ bf16_t Bs[128*64];

  const int tid  = threadIdx.x;
  const int wave = tid >> 6, lane = tid & 63;
  const int lrow = lane >> 3;                      // 0..7 row within chunk
  const int lcol = (((lane & 7) ^ lrow) * 8);      // swizzled k-offset (elements)

  const bf16_t* aptr[4];
  const bf16_t* bptr[4];
  #pragma unroll
  for (int j=0;j<4;j++){
    int chunk = wave*4 + j;            // 0..15, 8 rows each
    int r = chunk*8 + lrow;            // 0..127   (r&7 == lrow)
    int grow = m0 + r;
    if constexpr (G1){
      int tok = (grow < cn) ? stok[e*T_TOK + grow] : 0;
      aptr[j] = A0 + (size_t)tok*KD + lcol;
    } else {
      aptr[j] = A0 + (size_t)(oe + grow)*KD + lcol;  // padded rows read slack
    }
    bptr[j] = Bt + ((size_t)e*NR + (n0 + r))*KD + lcol;
  }

  f32x4 acc[4][4];
  #pragma unroll
  for (int mt=0;mt<4;mt++)
    #pragma unroll
    for (int nt=0;nt<4;nt++)
      #pragma unroll
      for (int q=0;q<4;q++) acc[mt][nt][q]=0.f;

  const int wm = wave & 1, wn = wave >> 1;
  const bf16_t* aslds = As + ((wm*64) + (lane & 15))*64;
  const bf16_t* bslds = Bs + ((wn*64) + (lane & 15))*64;
  // fragment-read swizzled k offsets for kc=0 and kc=32 (row&7 == lane&7)
  const int swz0 = ((((lane>>4) + 0) ^ (lane & 7)) * 8);
  const int swz1 = ((((lane>>4) + 4) ^ (lane & 7)) * 8);

  for (int k0=0; k0<KD; k0+=64){
    #pragma unroll
    for (int j=0;j<4;j++){
      gload_lds16(aptr[j] + k0, As + (wave*4+j)*512);
      gload_lds16(bptr[j] + k0, Bs + (wave*4+j)*512);
    }
    __syncthreads();
    #pragma unroll
    for (int kc=0;kc<64;kc+=32){
      const int swz = (kc == 0) ? swz0 : swz1;
      bf16x8 af[4], bfr[4];
      #pragma unroll
      for (int mt=0;mt<4;mt++) af[mt]  = *(const bf16x8*)(aslds + mt*1024 + swz);
      #pragma unroll
      for (int nt=0;nt<4;nt++) bfr[nt] = *(const bf16x8*)(bslds + nt*1024 + swz);
      #pragma unroll
      for (int mt=0;mt<4;mt++)
        #pragma unroll
        for (int nt=0;nt<4;nt++)
          acc[mt][nt] = __builtin_amdgcn_mfma_f32_16x16x32_bf16(af[mt], bfr[nt], acc[mt][nt], 0, 0, 0);
    }
    __syncthreads();
  }

  const int lq = lane >> 4;   // C/D: row = lq*4+i, col = lane&15
  const int lc = lane & 15;
  #pragma unroll
  for (int mt=0;mt<4;mt++){
    #pragma unroll
    for (int i=0;i<4;i++){
      int rl = wm*64 + mt*16 + lq*4 + i;
      int grow = m0 + rl;
      if (grow < cn){
        if constexpr (G1){
          float w = swgt[e*T_TOK + grow];
          size_t hbase = (size_t)(oe + grow) * FFD;
          #pragma unroll
          for (int nt=0;nt<4;nt++){
            int colg = n0 + wn*64 + nt*16 + lc;
            float vv = acc[mt][nt][i];
            vv = vv > 0.f ? vv * w : 0.f;     // relu, gate weight folded here
            Hout[hbase + colg] = (bf16_t)vv;
          }
        } else {
          size_t obase = (size_t)(oe + grow) * DIM;
          #pragma unroll
          for (int nt=0;nt<4;nt++){
            int colg = n0 + wn*64 + nt*16 + lc;
            Out[obase + colg] = acc[mt][nt][i];   // plain store, no atomics
          }
        }
      }
    }
  }
}

// ---------------- final combine: out = hidden + y2[slot0] + y2[slot1] --------
// Each token has exactly K=2 expert slots (recorded in tslot); gather both
// partial rows with float4 loads. Replaces residual memcpy + 16.7M atomics.
__global__ __launch_bounds__(256) void k_combine(
    const float* __restrict__ hidden, const float* __restrict__ y2,
    const int* __restrict__ offs, const int* __restrict__ tslot,
    float* __restrict__ out)
{
  const int t = blockIdx.x;
  const int tid = threadIdx.x;
  const int s0 = tslot[2*t+0], s1 = tslot[2*t+1];
  const size_t r0 = (size_t)(offs[s0>>16] + (s0 & 0xffff));
  const size_t r1 = (size_t)(offs[s1>>16] + (s1 & 0xffff));
  float4 a = ((const float4*)(hidden + (size_t)t*DIM))[tid];
  float4 b = ((const float4*)(y2 + r0*DIM))[tid];
  float4 c = ((const float4*)(y2 + r1*DIM))[tid];
  a.x += b.x + c.x;
  a.y += b.y + c.y;
  a.z += b.z + c.z;
  a.w += b.w + c.w;
  ((float4*)(out + (size_t)t*DIM))[tid] = a;
}

extern "C" void kernel_launch(void* const* d_in, const int* in_sizes, int n_in,
                              void* d_out, int out_size, void* d_ws, size_t ws_size,
                              hipStream_t stream) {
  const float* hidden = (const float*)d_in[0];
  const float* lnw    = (const float*)d_in[1];
  const float* gw     = (const float*)d_in[2];
  const float* gb     = (const float*)d_in[3];
  const float* wi     = (const float*)d_in[4];
  const float* wo     = (const float*)d_in[5];
  float* out = (float*)d_out;

  char* ws = (char*)d_ws;
  size_t o = 0;
  auto alloc = [&](size_t bytes)->char*{ char* p = ws + o; o += (bytes + 255) & ~(size_t)255; return p; };
  bf16_t* xt   = (bf16_t*)alloc((size_t)T_TOK*DIM*2);             //  16 MB
  bf16_t* wiT  = (bf16_t*)alloc((size_t)NEXP*FFD*DIM*2);          // 134 MB [E][FF][D]
  bf16_t* woT  = (bf16_t*)alloc((size_t)NEXP*DIM*FFD*2);          // 134 MB [E][D][FF]
  bf16_t* h    = (bf16_t*)alloc((size_t)(2*T_TOK + 128)*FFD*2);   // 135 MB (+slack)
  int*    stok = (int*)alloc((size_t)NEXP*T_TOK*4);
  float*  swgt = (float*)alloc((size_t)NEXP*T_TOK*4);
  int*    tslot= (int*)alloc((size_t)2*T_TOK*4);
  int*    cnt  = (int*)alloc(256);
  int*    offs = (int*)alloc(256);
  (void)ws_size; (void)in_sizes; (void)n_in; (void)out_size;

  // y2 (fp32 GEMM2 partials, 67.6 MB for 16512 rows) aliases the wiT region:
  // wiT is only read by k_gemm<G1=true>, which completes (stream order)
  // before k_gemm<G1=false> writes y2. Avoids growing the workspace.
  float* y2 = (float*)wiT;

  hipMemsetAsync(cnt, 0, 64, stream);

  k_norm_gate<<<dim3(T_TOK), 256, 0, stream>>>(hidden, lnw, gw, gb, xt, cnt, stok, swgt, tslot);
  k_offsets<<<dim3(1), 64, 0, stream>>>(cnt, offs);
  k_transpose<<<dim3(FFD/64, DIM/64, NEXP), 256, 0, stream>>>(wi, wiT, DIM, FFD);
  k_transpose<<<dim3(DIM/64, FFD/64, NEXP), 256, 0, stream>>>(wo, woT, FFD, DIM);
  k_gemm<DIM, true ><<<dim3(FFD/128, T_TOK/128, NEXP), 256, 0, stream>>>(xt, wiT, cnt, offs, stok, swgt, h, nullptr);
  k_gemm<FFD, false><<<dim3(DIM/128, T_TOK/128, NEXP), 256, 0, stream>>>(h,  woT, cnt, offs, stok, swgt, nullptr, y2);
  k_combine<<<dim3(T_TOK), 256, 0, stream>>>(hidden, y2, offs, tslot, out);
}

// Round 2
// 1212.188 us; speedup vs baseline: 1.0798x; 1.0798x over previous
//
#include <hip/hip_runtime.h>

#define T_TOK 8192
#define DIM   1024
#define FFD   4096
#define NEXP  16

typedef __bf16 bf16_t;
typedef bf16_t bf16x4 __attribute__((ext_vector_type(4)));
typedef bf16_t bf16x8 __attribute__((ext_vector_type(8)));
typedef float  f32x4  __attribute__((ext_vector_type(4)));

__device__ __forceinline__ void gload_lds16(const void* g, void* l) {
  __builtin_amdgcn_global_load_lds((__attribute__((address_space(1))) void*)(g),
                                   (__attribute__((address_space(3))) void*)(l),
                                   16, 0, 0);
}

// ---------------- RMSNorm + gate + top-2 routing (one block per token) -------
__global__ __launch_bounds__(256) void k_norm_gate(
    const float* __restrict__ x, const float* __restrict__ lnw,
    const float* __restrict__ gw, const float* __restrict__ gb,
    bf16_t* __restrict__ xt, int* __restrict__ cnt,
    int* __restrict__ stok, float* __restrict__ swgt,
    int* __restrict__ tslot)
{
  const int t = blockIdx.x;
  const int tid = threadIdx.x;
  const int wave = tid >> 6, lane = tid & 63;

  float4 v = ((const float4*)(x + (size_t)t * DIM))[tid];
  float ss = v.x*v.x + v.y*v.y + v.z*v.z + v.w*v.w;
  #pragma unroll
  for (int off = 32; off > 0; off >>= 1) ss += __shfl_down(ss, off, 64);

  __shared__ float red[4];
  __shared__ float racc[4][16];
  __shared__ int   sel[2];
  __shared__ float swv[2];
  if (lane == 0) red[wave] = ss;
  __syncthreads();
  float r = rsqrtf((red[0]+red[1]+red[2]+red[3]) * (1.0f/DIM) + 1e-6f);

  float4 lw = ((const float4*)lnw)[tid];
  float nv[4];
  nv[0] = v.x*r*lw.x; nv[1] = v.y*r*lw.y; nv[2] = v.z*r*lw.z; nv[3] = v.w*r*lw.w;
  bf16x4 nb; nb[0]=(bf16_t)nv[0]; nb[1]=(bf16_t)nv[1]; nb[2]=(bf16_t)nv[2]; nb[3]=(bf16_t)nv[3];
  ((bf16x4*)(xt + (size_t)t * DIM))[tid] = nb;

  // gate logits: fp32 (expert-selection must match np reference)
  float acc[16];
  #pragma unroll
  for (int e=0;e<16;e++) acc[e]=0.f;
  #pragma unroll
  for (int j=0;j<4;j++){
    const float4* row = (const float4*)(gw + ((size_t)(tid*4+j))*16);
    #pragma unroll
    for (int q=0;q<4;q++){
      float4 g = row[q];
      acc[q*4+0] += nv[j]*g.x;
      acc[q*4+1] += nv[j]*g.y;
      acc[q*4+2] += nv[j]*g.z;
      acc[q*4+3] += nv[j]*g.w;
    }
  }
  #pragma unroll
  for (int e=0;e<16;e++){
    #pragma unroll
    for (int off=32;off>0;off>>=1) acc[e] += __shfl_down(acc[e], off, 64);
  }
  if (lane==0){
    #pragma unroll
    for (int e=0;e<16;e++) racc[wave][e]=acc[e];
  }
  __syncthreads();
  if (tid==0){
    float lg[16];
    #pragma unroll
    for (int e=0;e<16;e++) lg[e] = racc[0][e]+racc[1][e]+racc[2][e]+racc[3][e] + gb[e];
    int i0=0; float v0=lg[0];
    for (int e=1;e<16;e++) if (lg[e]>v0){v0=lg[e]; i0=e;}
    int i1=-1; float v1=-3.4e38f;
    for (int e=0;e<16;e++) if (e!=i0 && lg[e]>v1){v1=lg[e]; i1=e;}
    float ex = expf(v1-v0);
    float s0 = 1.0f/(1.0f+ex);
    float s1 = ex * s0;
    sel[0]=i0; sel[1]=i1; swv[0]=s0; swv[1]=s1;
  }
  __syncthreads();
  if (tid<2){   // two independent atomics issue in one wave-instruction
    int ii = sel[tid]; float sv = swv[tid];
    int p = atomicAdd(&cnt[ii],1);
    stok[ii*T_TOK+p]=t; swgt[ii*T_TOK+p]=sv;
    tslot[2*t+tid] = (ii<<16) | p;    // expert hi16, slot lo16
  }
}

// ---------------- tiny prefix sum over 16 expert counts ----------------------
__global__ void k_offsets(const int* __restrict__ cnt, int* __restrict__ offs){
  if (threadIdx.x==0){
    int s=0;
    for (int e=0;e<NEXP;e++){ offs[e]=s; s+=cnt[e]; }
    offs[NEXP]=s;
  }
}

// ---------------- merged fp32 [E][R][C] -> bf16 [E][C][R] for wi AND wo ------
// bf16 LDS tile with XOR swizzle (c ^= ((r>>3)&7)<<3): column reads hit all 32
// banks (row stride 128B alone would put 8 lanes on one bank). 16B/lane stores.
__global__ __launch_bounds__(256) void k_transpose2(
    const float* __restrict__ wi, bf16_t* __restrict__ wiT,
    const float* __restrict__ wo, bf16_t* __restrict__ woT)
{
  __shared__ bf16_t lds[64*64];
  const int z = blockIdx.z;
  const float* in; bf16_t* out; int R, C, bx, by, e;
  if (z < NEXP){ in=wi; out=wiT; R=DIM; C=FFD; e=z;
                 bx=blockIdx.x; by=blockIdx.y; }           // grid 64x16
  else        { in=wo; out=woT; R=FFD; C=DIM; e=z-NEXP;
                 bx=blockIdx.x & 15; by=blockIdx.y + 16*(blockIdx.x>>4); } // 16x64
  const int r0 = by*64, c0 = bx*64;
  const int tid = threadIdx.x;

  { // phase 1: fp32 read (256B/16 lanes), convert, swizzled bf16x4 LDS store
    const int rr = tid >> 4;            // 0..15
    const int c4 = (tid & 15) * 4;      // 0..60
    const float* src = in + ((size_t)e*R + r0 + rr)*C + c0 + c4;
    #pragma unroll
    for (int i=0;i<4;i++){
      int rrow = rr + i*16;
      float4 vv = *(const float4*)(src + (size_t)i*16*C);
      bf16x4 b; b[0]=(bf16_t)vv.x; b[1]=(bf16_t)vv.y; b[2]=(bf16_t)vv.z; b[3]=(bf16_t)vv.w;
      int swz = ((rrow >> 3) & 7) << 3;
      *(bf16x4*)(lds + rrow*64 + (c4 ^ swz)) = b;
    }
  }
  __syncthreads();
  { // phase 2: conflict-free column gather, bf16x8 (16B/lane) global store
    const int r8  = (tid & 7) * 8;
    const int cc  = tid >> 3;           // 0..31
    const int swz = (tid & 7) << 3;     // == ((r8+j)>>3 & 7)<<3 for j=0..7
    #pragma unroll
    for (int i=0;i<2;i++){
      int c = cc + i*32;
      bf16x8 b;
      #pragma unroll
      for (int j=0;j<8;j++) b[j] = lds[(r8+j)*64 + (c ^ swz)];
      *(bf16x8*)(out + ((size_t)e*C + c0 + c)*R + r0 + r8) = b;
    }
  }
}

// ---------------- routed GEMM (m97 structure), 128x128 tile, BK=64 -----------
// LDS K-blocks XOR-swizzled via pre-swizzled global source column (gload_lds
// dest is HW-fixed); undone at fragment read. G1: h=relu(xt@wiT^T)*gate;
// !G1: y2 = h@woT^T (plain fp32 stores; combine handles the K=2 scatter).
template<int KD, bool G1>
__global__ __launch_bounds__(256) void k_gemm(
    const bf16_t* __restrict__ A0, const bf16_t* __restrict__ Bt,
    const int* __restrict__ cnt, const int* __restrict__ offs,
    const int* __restrict__ stok, const float* __restrict__ swgt,
    bf16_t* __restrict__ Hout, float* __restrict__ Out)
{
  const int e  = blockIdx.z;
  const int cn = cnt[e];
  const int m0 = blockIdx.y * 128;
  if (m0 >= cn) return;
  const int n0 = blockIdx.x * 128;
  const int oe = offs[e];
  constexpr int NR = G1 ? FFD : DIM;

  __shared__ bf16_t As[128*64];
  __shared__ bf16_t Bs[128*64];

  const int tid  = threadIdx.x;
  const int wave = tid >> 6, lane = tid & 63;
  const int lrow = lane >> 3;
  const int lcol = (((lane & 7) ^ lrow) * 8);

  const bf16_t* aptr[4];
  const bf16_t* bptr[4];
  #pragma unroll
  for (int j=0;j<4;j++){
    int chunk = wave*4 + j;
    int r = chunk*8 + lrow;
    int grow = m0 + r;
    if constexpr (G1){
      int tok = (grow < cn) ? stok[e*T_TOK + grow] : 0;
      aptr[j] = A0 + (size_t)tok*KD + lcol;
    } else {
      aptr[j] = A0 + (size_t)(oe + grow)*KD + lcol;
    }
    bptr[j] = Bt + ((size_t)e*NR + (n0 + r))*KD + lcol;
  }

  f32x4 acc[4][4];
  #pragma unroll
  for (int mt=0;mt<4;mt++)
    #pragma unroll
    for (int nt=0;nt<4;nt++)
      #pragma unroll
      for (int q=0;q<4;q++) acc[mt][nt][q]=0.f;

  const int wm = wave & 1, wn = wave >> 1;
  const bf16_t* aslds = As + ((wm*64) + (lane & 15))*64;
  const bf16_t* bslds = Bs + ((wn*64) + (lane & 15))*64;
  const int swz0 = ((((lane>>4) + 0) ^ (lane & 7)) * 8);
  const int swz1 = ((((lane>>4) + 4) ^ (lane & 7)) * 8);

  for (int k0=0; k0<KD; k0+=64){
    #pragma unroll
    for (int j=0;j<4;j++){
      gload_lds16(aptr[j] + k0, As + (wave*4+j)*512);
      gload_lds16(bptr[j] + k0, Bs + (wave*4+j)*512);
    }
    __syncthreads();
    #pragma unroll
    for (int kc=0;kc<64;kc+=32){
      const int swz = (kc == 0) ? swz0 : swz1;
      bf16x8 af[4], bfr[4];
      #pragma unroll
      for (int mt=0;mt<4;mt++) af[mt]  = *(const bf16x8*)(aslds + mt*1024 + swz);
      #pragma unroll
      for (int nt=0;nt<4;nt++) bfr[nt] = *(const bf16x8*)(bslds + nt*1024 + swz);
      #pragma unroll
      for (int mt=0;mt<4;mt++)
        #pragma unroll
        for (int nt=0;nt<4;nt++)
          acc[mt][nt] = __builtin_amdgcn_mfma_f32_16x16x32_bf16(af[mt], bfr[nt], acc[mt][nt], 0, 0, 0);
    }
    __syncthreads();
  }

  const int lq = lane >> 4;
  const int lc = lane & 15;
  #pragma unroll
  for (int mt=0;mt<4;mt++){
    #pragma unroll
    for (int i=0;i<4;i++){
      int rl = wm*64 + mt*16 + lq*4 + i;
      int grow = m0 + rl;
      if (grow < cn){
        if constexpr (G1){
          float w = swgt[e*T_TOK + grow];
          size_t hbase = (size_t)(oe + grow) * FFD;
          #pragma unroll
          for (int nt=0;nt<4;nt++){
            int colg = n0 + wn*64 + nt*16 + lc;
            float vv = acc[mt][nt][i];
            vv = vv > 0.f ? vv * w : 0.f;
            Hout[hbase + colg] = (bf16_t)vv;
          }
        } else {
          size_t obase = (size_t)(oe + grow) * DIM;
          #pragma unroll
          for (int nt=0;nt<4;nt++){
            int colg = n0 + wn*64 + nt*16 + lc;
            Out[obase + colg] = acc[mt][nt][i];
          }
        }
      }
    }
  }
}

// ---------------- final combine: out = hidden + y2[slot0] + y2[slot1] --------
__global__ __launch_bounds__(256) void k_combine(
    const float* __restrict__ hidden, const float* __restrict__ y2,
    const int* __restrict__ offs, const int* __restrict__ tslot,
    float* __restrict__ out)
{
  const int t = blockIdx.x;
  const int tid = threadIdx.x;
  const int s0 = tslot[2*t+0], s1 = tslot[2*t+1];
  const size_t r0 = (size_t)(offs[s0>>16] + (s0 & 0xffff));
  const size_t r1 = (size_t)(offs[s1>>16] + (s1 & 0xffff));
  float4 a = ((const float4*)(hidden + (size_t)t*DIM))[tid];
  float4 b = ((const float4*)(y2 + r0*DIM))[tid];
  float4 c = ((const float4*)(y2 + r1*DIM))[tid];
  a.x += b.x + c.x;
  a.y += b.y + c.y;
  a.z += b.z + c.z;
  a.w += b.w + c.w;
  ((float4*)(out + (size_t)t*DIM))[tid] = a;
}

extern "C" void kernel_launch(void* const* d_in, const int* in_sizes, int n_in,
                              void* d_out, int out_size, void* d_ws, size_t ws_size,
                              hipStream_t stream) {
  const float* hidden = (const float*)d_in[0];
  const float* lnw    = (const float*)d_in[1];
  const float* gw     = (const float*)d_in[2];
  const float* gb     = (const float*)d_in[3];
  const float* wi     = (const float*)d_in[4];
  const float* wo     = (const float*)d_in[5];
  float* out = (float*)d_out;

  char* ws = (char*)d_ws;
  size_t o = 0;
  auto alloc = [&](size_t bytes)->char*{ char* p = ws + o; o += (bytes + 255) & ~(size_t)255; return p; };
  bf16_t* xt   = (bf16_t*)alloc((size_t)T_TOK*DIM*2);             //  16 MB
  bf16_t* wiT  = (bf16_t*)alloc((size_t)NEXP*FFD*DIM*2);          // 134 MB [E][FF][D]
  bf16_t* woT  = (bf16_t*)alloc((size_t)NEXP*DIM*FFD*2);          // 134 MB [E][D][FF]
  bf16_t* h    = (bf16_t*)alloc((size_t)(2*T_TOK + 128)*FFD*2);   // 135 MB (+slack)
  int*    stok = (int*)alloc((size_t)NEXP*T_TOK*4);
  float*  swgt = (float*)alloc((size_t)NEXP*T_TOK*4);
  int*    tslot= (int*)alloc((size_t)2*T_TOK*4);
  int*    cnt  = (int*)alloc(256);
  int*    offs = (int*)alloc(256);
  (void)ws_size; (void)in_sizes; (void)n_in; (void)out_size;

  // y2 (fp32 GEMM2 partials) aliases wiT: wiT is dead after k_gemm<G1=true>.
  float* y2 = (float*)wiT;

  hipMemsetAsync(cnt, 0, 64, stream);

  k_norm_gate<<<dim3(T_TOK), 256, 0, stream>>>(hidden, lnw, gw, gb, xt, cnt, stok, swgt, tslot);
  k_offsets<<<dim3(1), 64, 0, stream>>>(cnt, offs);
  k_transpose2<<<dim3(64, 16, 2*NEXP), 256, 0, stream>>>(wi, wiT, wo, woT);
  k_gemm<DIM, true ><<<dim3(FFD/128, T_TOK/128, NEXP), 256, 0, stream>>>(xt, wiT, cnt, offs, stok, swgt, h, nullptr);
  k_gemm<FFD, false><<<dim3(DIM/128, T_TOK/128, NEXP), 256, 0, stream>>>(h,  woT, cnt, offs, stok, swgt, nullptr, y2);
  k_combine<<<dim3(T_TOK), 256, 0, stream>>>(hidden, y2, offs, tslot, out);
}

// Round 3
// 1191.284 us; speedup vs baseline: 1.0988x; 1.0175x over previous
//
#include <hip/hip_runtime.h>

#define T_TOK 8192
#define DIM   1024
#define FFD   4096
#define NEXP  16

typedef __bf16 bf16_t;
typedef bf16_t bf16x4 __attribute__((ext_vector_type(4)));
typedef bf16_t bf16x8 __attribute__((ext_vector_type(8)));
typedef float  f32x4  __attribute__((ext_vector_type(4)));

__device__ __forceinline__ void gload_lds16(const void* g, void* l) {
  __builtin_amdgcn_global_load_lds((__attribute__((address_space(1))) void*)(g),
                                   (__attribute__((address_space(3))) void*)(l),
                                   16, 0, 0);
}

// ---------------- RMSNorm + gate + top-2 routing (one block per token) -------
__global__ __launch_bounds__(256) void k_norm_gate(
    const float* __restrict__ x, const float* __restrict__ lnw,
    const float* __restrict__ gw, const float* __restrict__ gb,
    bf16_t* __restrict__ xt, int* __restrict__ cnt,
    int* __restrict__ stok, float* __restrict__ swgt,
    int* __restrict__ tslot)
{
  const int t = blockIdx.x;
  const int tid = threadIdx.x;
  const int wave = tid >> 6, lane = tid & 63;

  float4 v = ((const float4*)(x + (size_t)t * DIM))[tid];
  float ss = v.x*v.x + v.y*v.y + v.z*v.z + v.w*v.w;
  #pragma unroll
  for (int off = 32; off > 0; off >>= 1) ss += __shfl_down(ss, off, 64);

  __shared__ float red[4];
  __shared__ float racc[4][16];
  __shared__ int   sel[2];
  __shared__ float swv[2];
  if (lane == 0) red[wave] = ss;
  __syncthreads();
  float r = rsqrtf((red[0]+red[1]+red[2]+red[3]) * (1.0f/DIM) + 1e-6f);

  float4 lw = ((const float4*)lnw)[tid];
  float nv[4];
  nv[0] = v.x*r*lw.x; nv[1] = v.y*r*lw.y; nv[2] = v.z*r*lw.z; nv[3] = v.w*r*lw.w;
  bf16x4 nb; nb[0]=(bf16_t)nv[0]; nb[1]=(bf16_t)nv[1]; nb[2]=(bf16_t)nv[2]; nb[3]=(bf16_t)nv[3];
  ((bf16x4*)(xt + (size_t)t * DIM))[tid] = nb;

  float acc[16];
  #pragma unroll
  for (int e=0;e<16;e++) acc[e]=0.f;
  #pragma unroll
  for (int j=0;j<4;j++){
    const float4* row = (const float4*)(gw + ((size_t)(tid*4+j))*16);
    #pragma unroll
    for (int q=0;q<4;q++){
      float4 g = row[q];
      acc[q*4+0] += nv[j]*g.x;
      acc[q*4+1] += nv[j]*g.y;
      acc[q*4+2] += nv[j]*g.z;
      acc[q*4+3] += nv[j]*g.w;
    }
  }
  #pragma unroll
  for (int e=0;e<16;e++){
    #pragma unroll
    for (int off=32;off>0;off>>=1) acc[e] += __shfl_down(acc[e], off, 64);
  }
  if (lane==0){
    #pragma unroll
    for (int e=0;e<16;e++) racc[wave][e]=acc[e];
  }
  __syncthreads();
  if (tid==0){
    float lg[16];
    #pragma unroll
    for (int e=0;e<16;e++) lg[e] = racc[0][e]+racc[1][e]+racc[2][e]+racc[3][e] + gb[e];
    int i0=0; float v0=lg[0];
    for (int e=1;e<16;e++) if (lg[e]>v0){v0=lg[e]; i0=e;}
    int i1=-1; float v1=-3.4e38f;
    for (int e=0;e<16;e++) if (e!=i0 && lg[e]>v1){v1=lg[e]; i1=e;}
    float ex = expf(v1-v0);
    float s0 = 1.0f/(1.0f+ex);
    float s1 = ex * s0;
    sel[0]=i0; sel[1]=i1; swv[0]=s0; swv[1]=s1;
  }
  __syncthreads();
  if (tid<2){
    int ii = sel[tid]; float sv = swv[tid];
    int p = atomicAdd(&cnt[ii],1);
    stok[ii*T_TOK+p]=t; swgt[ii*T_TOK+p]=sv;
    tslot[2*t+tid] = (ii<<16) | p;
  }
}

// ---------------- tiny prefix sum over 16 expert counts ----------------------
__global__ void k_offsets(const int* __restrict__ cnt, int* __restrict__ offs){
  if (threadIdx.x==0){
    int s=0;
    for (int e=0;e<NEXP;e++){ offs[e]=s; s+=cnt[e]; }
    offs[NEXP]=s;
  }
}

// ---------------- merged fp32 [E][R][C] -> bf16 [E][C][R] for wi AND wo ------
__global__ __launch_bounds__(256) void k_transpose2(
    const float* __restrict__ wi, bf16_t* __restrict__ wiT,
    const float* __restrict__ wo, bf16_t* __restrict__ woT)
{
  __shared__ bf16_t lds[64*64];
  const int z = blockIdx.z;
  const float* in; bf16_t* out; int R, C, bx, by, e;
  if (z < NEXP){ in=wi; out=wiT; R=DIM; C=FFD; e=z;
                 bx=blockIdx.x; by=blockIdx.y; }
  else        { in=wo; out=woT; R=FFD; C=DIM; e=z-NEXP;
                 bx=blockIdx.x & 15; by=blockIdx.y + 16*(blockIdx.x>>4); }
  const int r0 = by*64, c0 = bx*64;
  const int tid = threadIdx.x;

  {
    const int rr = tid >> 4;
    const int c4 = (tid & 15) * 4;
    const float* src = in + ((size_t)e*R + r0 + rr)*C + c0 + c4;
    #pragma unroll
    for (int i=0;i<4;i++){
      int rrow = rr + i*16;
      float4 vv = *(const float4*)(src + (size_t)i*16*C);
      bf16x4 b; b[0]=(bf16_t)vv.x; b[1]=(bf16_t)vv.y; b[2]=(bf16_t)vv.z; b[3]=(bf16_t)vv.w;
      int swz = ((rrow >> 3) & 7) << 3;
      *(bf16x4*)(lds + rrow*64 + (c4 ^ swz)) = b;
    }
  }
  __syncthreads();
  {
    const int r8  = (tid & 7) * 8;
    const int cc  = tid >> 3;
    const int swz = (tid & 7) << 3;
    #pragma unroll
    for (int i=0;i<2;i++){
      int c = cc + i*32;
      bf16x8 b;
      #pragma unroll
      for (int j=0;j<8;j++) b[j] = lds[(r8+j)*64 + (c ^ swz)];
      *(bf16x8*)(out + ((size_t)e*C + c0 + c)*R + r0 + r8) = b;
    }
  }
}

// ---------------- routed GEMM, 2-phase double-buffered (T3-minimum) ----------
// G1: 256x256 tile, 512 thr / 8 waves.  !G1: 128x128 tile, 256 thr / 4 waves.
// Per K-step: issue next tile's global_load_lds, compute current from LDS,
// then ONE __syncthreads (its implicit vmcnt(0) drains the prefetch after
// compute has hidden its latency).  XOR-swizzle: pre-swizzled global source
// column at staging (gload_lds LDS dest is HW-linear), undone at frag read.
template<int KD, bool G1>
__global__ __launch_bounds__(G1?512:256, 2) void k_gemm(
    const bf16_t* __restrict__ A0, const bf16_t* __restrict__ Bt,
    const int* __restrict__ cnt, const int* __restrict__ offs,
    const int* __restrict__ stok, const float* __restrict__ swgt,
    bf16_t* __restrict__ Hout, float* __restrict__ Out)
{
  constexpr int BM = G1 ? 256 : 128;
  constexpr int BN = G1 ? 256 : 128;
  constexpr int MT = G1 ? 8 : 4;       // 16-row frags per wave (M)
  constexpr int NT = 4;                // 16-col frags per wave (N)
  constexpr int NK = KD / 64;
  constexpr int NR = G1 ? FFD : DIM;

  const int e  = blockIdx.z;
  const int cn = cnt[e];
  const int m0 = blockIdx.y * BM;
  if (m0 >= cn) return;
  const int n0 = blockIdx.x * BN;
  const int oe = offs[e];

  __shared__ bf16_t As[2][BM*64];
  __shared__ bf16_t Bs[2][BN*64];

  const int tid  = threadIdx.x;
  const int wave = tid >> 6, lane = tid & 63;
  const int lrow = lane >> 3;
  const int lcol = (((lane & 7) ^ lrow) * 8);

  const bf16_t* aptr[4];
  const bf16_t* bptr[4];
  #pragma unroll
  for (int j=0;j<4;j++){
    int chunk = wave*4 + j;            // covers BM/8 chunks of 8 rows
    int r = chunk*8 + lrow;            // r&7 == lrow
    int grow = m0 + r;
    if constexpr (G1){
      int tok = (grow < cn) ? stok[e*T_TOK + grow] : 0;
      aptr[j] = A0 + (size_t)tok*KD + lcol;
    } else {
      aptr[j] = A0 + (size_t)(oe + grow)*KD + lcol;  // slack rows read junk, discarded
    }
    bptr[j] = Bt + ((size_t)e*NR + (n0 + r))*KD + lcol;
  }

  auto stage = [&](int buf, int kof){
    #pragma unroll
    for (int j=0;j<4;j++){
      gload_lds16(aptr[j] + kof, &As[buf][(wave*4+j)*512]);
      gload_lds16(bptr[j] + kof, &Bs[buf][(wave*4+j)*512]);
    }
  };

  f32x4 acc[MT][NT];
  #pragma unroll
  for (int mt=0;mt<MT;mt++)
    #pragma unroll
    for (int nt=0;nt<NT;nt++)
      #pragma unroll
      for (int q=0;q<4;q++) acc[mt][nt][q]=0.f;

  const int wm = wave & 1, wn = wave >> 1;   // G1: wn 0..3, G2: wn 0..1
  const int swz0 = ((((lane>>4) + 0) ^ (lane & 7)) * 8);
  const int swz1 = ((((lane>>4) + 4) ^ (lane & 7)) * 8);

  stage(0, 0);
  __syncthreads();

  for (int kt=0; kt<NK; ++kt){
    if (kt+1 < NK) stage((kt+1)&1, (kt+1)*64);   // prefetch next tile
    const int cur = kt & 1;
    const bf16_t* aslds = &As[cur][(wm*(BM/2) + (lane & 15))*64];
    const bf16_t* bslds = &Bs[cur][(wn*64     + (lane & 15))*64];
    #pragma unroll
    for (int kc=0;kc<64;kc+=32){
      const int swz = (kc == 0) ? swz0 : swz1;
      bf16x8 af[MT], bfr[NT];
      #pragma unroll
      for (int mt=0;mt<MT;mt++) af[mt]  = *(const bf16x8*)(aslds + mt*1024 + swz);
      #pragma unroll
      for (int nt=0;nt<NT;nt++) bfr[nt] = *(const bf16x8*)(bslds + nt*1024 + swz);
      #pragma unroll
      for (int mt=0;mt<MT;mt++)
        #pragma unroll
        for (int nt=0;nt<NT;nt++)
          acc[mt][nt] = __builtin_amdgcn_mfma_f32_16x16x32_bf16(af[mt], bfr[nt], acc[mt][nt], 0, 0, 0);
    }
    __syncthreads();   // implicit vmcnt(0): prefetch drained; cur reads done
  }

  const int lq = lane >> 4;
  const int lc = lane & 15;
  #pragma unroll
  for (int mt=0;mt<MT;mt++){
    #pragma unroll
    for (int i=0;i<4;i++){
      int rl = wm*(BM/2) + mt*16 + lq*4 + i;
      int grow = m0 + rl;
      if (grow < cn){
        if constexpr (G1){
          float w = swgt[e*T_TOK + grow];
          size_t hbase = (size_t)(oe + grow) * FFD;
          #pragma unroll
          for (int nt=0;nt<NT;nt++){
            int colg = n0 + wn*64 + nt*16 + lc;
            float vv = acc[mt][nt][i];
            vv = vv > 0.f ? vv * w : 0.f;
            Hout[hbase + colg] = (bf16_t)vv;
          }
        } else {
          size_t obase = (size_t)(oe + grow) * DIM;
          #pragma unroll
          for (int nt=0;nt<NT;nt++){
            int colg = n0 + wn*64 + nt*16 + lc;
            Out[obase + colg] = acc[mt][nt][i];
          }
        }
      }
    }
  }
}

// ---------------- final combine: out = hidden + y2[slot0] + y2[slot1] --------
__global__ __launch_bounds__(256) void k_combine(
    const float* __restrict__ hidden, const float* __restrict__ y2,
    const int* __restrict__ offs, const int* __restrict__ tslot,
    float* __restrict__ out)
{
  const int t = blockIdx.x;
  const int tid = threadIdx.x;
  const int s0 = tslot[2*t+0], s1 = tslot[2*t+1];
  const size_t r0 = (size_t)(offs[s0>>16] + (s0 & 0xffff));
  const size_t r1 = (size_t)(offs[s1>>16] + (s1 & 0xffff));
  float4 a = ((const float4*)(hidden + (size_t)t*DIM))[tid];
  float4 b = ((const float4*)(y2 + r0*DIM))[tid];
  float4 c = ((const float4*)(y2 + r1*DIM))[tid];
  a.x += b.x + c.x;
  a.y += b.y + c.y;
  a.z += b.z + c.z;
  a.w += b.w + c.w;
  ((float4*)(out + (size_t)t*DIM))[tid] = a;
}

extern "C" void kernel_launch(void* const* d_in, const int* in_sizes, int n_in,
                              void* d_out, int out_size, void* d_ws, size_t ws_size,
                              hipStream_t stream) {
  const float* hidden = (const float*)d_in[0];
  const float* lnw    = (const float*)d_in[1];
  const float* gw     = (const float*)d_in[2];
  const float* gb     = (const float*)d_in[3];
  const float* wi     = (const float*)d_in[4];
  const float* wo     = (const float*)d_in[5];
  float* out = (float*)d_out;

  char* ws = (char*)d_ws;
  size_t o = 0;
  auto alloc = [&](size_t bytes)->char*{ char* p = ws + o; o += (bytes + 255) & ~(size_t)255; return p; };
  bf16_t* xt   = (bf16_t*)alloc((size_t)T_TOK*DIM*2);             //  16 MB
  bf16_t* wiT  = (bf16_t*)alloc((size_t)NEXP*FFD*DIM*2);          // 134 MB [E][FF][D]
  bf16_t* woT  = (bf16_t*)alloc((size_t)NEXP*DIM*FFD*2);          // 134 MB [E][D][FF]
  bf16_t* h    = (bf16_t*)alloc((size_t)(2*T_TOK + 256)*FFD*2);   // 135 MB (+slack)
  int*    stok = (int*)alloc((size_t)NEXP*T_TOK*4);
  float*  swgt = (float*)alloc((size_t)NEXP*T_TOK*4);
  int*    tslot= (int*)alloc((size_t)2*T_TOK*4);
  int*    cnt  = (int*)alloc(256);
  int*    offs = (int*)alloc(256);
  (void)ws_size; (void)in_sizes; (void)n_in; (void)out_size;

  // y2 (fp32 GEMM2 partials) aliases wiT: wiT is dead after k_gemm<G1=true>.
  float* y2 = (float*)wiT;

  hipMemsetAsync(cnt, 0, 64, stream);

  k_norm_gate<<<dim3(T_TOK), 256, 0, stream>>>(hidden, lnw, gw, gb, xt, cnt, stok, swgt, tslot);
  k_offsets<<<dim3(1), 64, 0, stream>>>(cnt, offs);
  k_transpose2<<<dim3(64, 16, 2*NEXP), 256, 0, stream>>>(wi, wiT, wo, woT);
  k_gemm<DIM, true ><<<dim3(FFD/256, T_TOK/256, NEXP), 512, 0, stream>>>(xt, wiT, cnt, offs, stok, swgt, h, nullptr);
  k_gemm<FFD, false><<<dim3(DIM/128, T_TOK/128, NEXP), 256, 0, stream>>>(h,  woT, cnt, offs, stok, swgt, nullptr, y2);
  k_combine<<<dim3(T_TOK), 256, 0, stream>>>(hidden, y2, offs, tslot, out);
}